// Round 14
// baseline (73.552 us; speedup 1.0000x reference)
//
#include <hip/hip_runtime.h>

#define O_ 2048
#define M_ 512
#define FIN 64
#define FMAS 64
#define DOUT 32
#define H_ 128
#define TD 96
#define NB_ 3

typedef __attribute__((ext_vector_type(4))) float f32x4;
typedef __attribute__((ext_vector_type(8))) short bf16x8;

__device__ __forceinline__ float elu_f(float x) {
    return x > 0.f ? x : (__expf(x) - 1.f);
}
__device__ __forceinline__ unsigned short f2b(float x) {
    union { float f; unsigned u; } uu; uu.f = x;
    unsigned r = uu.u + 0x7fffu + ((uu.u >> 16) & 1u);
    return (unsigned short)(r >> 16);
}
__device__ __forceinline__ float b2f(unsigned short s) {
    union { float f; unsigned u; } uu; uu.u = ((unsigned)s) << 16;
    return uu.f;
}
__device__ __forceinline__ void splitw(float x, short& h, short& lo) {
    unsigned u = __float_as_uint(x);
    unsigned short hi = (unsigned short)(u >> 16);
    float rem = x - b2f(hi);
    h = (short)hi;
    lo = (short)(unsigned short)(__float_as_uint(rem) >> 16);
}

// ---------------------------------------------------------------------------
// PREP (143 blocks): blocks 0..14 = weight fragment tables + scalars;
// blocks 15..142 = per-li bf16 H fragment tables (khf).
// ---------------------------------------------------------------------------
__global__ __launch_bounds__(256) void prep(
        const float* __restrict__ e_w1, const float* __restrict__ e_b1,
        const float* __restrict__ e_w2, const float* __restrict__ e_b2,
        const float* __restrict__ coeff, const float* __restrict__ v,
        const float* __restrict__ w0w1, const float* __restrict__ w0w2,
        const float* __restrict__ om1, const float* __restrict__ hmas,
        const int* __restrict__ bidx,
        float* __restrict__ ws_scal,
        bf16x8* __restrict__ w1f, bf16x8* __restrict__ w2f,
        bf16x8* __restrict__ wth, bf16x8* __restrict__ wtl,
        bf16x8* __restrict__ o1h, bf16x8* __restrict__ o1l,
        bf16x8* __restrict__ hf) {
    const int t = threadIdx.x;
    if (blockIdx.x < 15) {
        __shared__ float r1[128], r2[128];
        if (t < 128) { r1[t] = e_w1[t] * e_w2[t]; r2[t] = e_b1[t] * e_w2[t]; }
        __syncthreads();
        for (int s = 64; s > 0; s >>= 1) {
            if (t < s) { r1[t] += r1[t + s]; r2[t] += r2[t + s]; }
            __syncthreads();
        }
        if (blockIdx.x == 0 && t == 0) {
            ws_scal[0] = r1[0];
            ws_scal[1] = r2[0] + e_b2[0];
        }
        const int e = blockIdx.x * 256 + t;       // [0, 3840)
        const int le = e & 63, cc = le & 15, gg = le >> 4;
        if (e < 1024) {
            int nf = e >> 7, ks = (e >> 6) & 1;
            bf16x8 vv;
            #pragma unroll
            for (int j = 0; j < 8; ++j)
                vv[j] = (short)f2b(w0w1[(ks * 32 + gg * 8 + j) * H_ + nf * 16 + cc]);
            w1f[e] = vv;
        } else if (e < 1536) {
            int e2 = e - 1024;
            int nf = e2 >> 8, ks = (e2 >> 6) & 3;
            bf16x8 vv;
            #pragma unroll
            for (int j = 0; j < 8; ++j)
                vv[j] = (short)f2b(w0w2[(ks * 32 + gg * 8 + j) * DOUT + nf * 16 + cc]);
            w2f[e2] = vv;
        } else if (e < 2304) {
            int e3 = e - 1536;
            int nf = e3 >> 7, ks = (e3 >> 6) & 1;
            bf16x8 vh, vl;
            #pragma unroll
            for (int j = 0; j < 8; ++j) {
                int row = ks * 32 + gg * 8 + j;
                int col = nf * 16 + cc;
                int tt = col >> 5, ee = col & 31;
                float s = 0.f;
                #pragma unroll
                for (int nb = 0; nb < NB_; ++nb)
                    s += coeff[tt * NB_ + nb] * v[(nb * FMAS + row) * DOUT + ee];
                short h, lo; splitw(s, h, lo);
                vh[j] = h; vl[j] = lo;
            }
            wth[e3] = vh; wtl[e3] = vl;
        } else if (e < 3840) {
            int e4 = e - 2304;
            int nf = e4 / 192, r = e4 % 192, ks = r >> 6;
            bf16x8 vh, vl;
            #pragma unroll
            for (int j = 0; j < 8; ++j) {
                float vv = om1[(ks * 32 + gg * 8 + j) * H_ + nf * 16 + cc];
                short h, lo; splitw(vv, h, lo);
                vh[j] = h; vl[j] = lo;
            }
            o1h[e4] = vh; o1l[e4] = vl;
        }
    } else {
        const int b2 = blockIdx.x - 15;
        const int li = b2 >> 2;
        const int part = b2 & 3;
        const int bi = bidx[li];
        const float* hb = hmas + (long long)bi * M_ * FMAS;
        bf16x8* dst = hf + li * 4096;
        #pragma unroll
        for (int j4 = 0; j4 < 4; ++j4) {
            int e = part * 1024 + j4 * 256 + t;
            int ft = e >> 10, ks = (e >> 6) & 15, le = e & 63;
            int cc = le & 15, gg = le >> 4;
            const float* src = hb + (ks * 32 + gg * 8) * FMAS + ft * 16 + cc;
            bf16x8 vv;
            #pragma unroll
            for (int j = 0; j < 8; ++j) vv[j] = (short)f2b(src[j * FMAS]);
            dst[e] = vv;
        }
    }
}

// ---------------------------------------------------------------------------
// GFUSED: per wave = 16 complete output rows; no barriers anywhere.
// Phase A (stream): agg = (mask*(ke*feat2+ce)) @ H -- LDS-staged A-tile,
//   XOR-swizzled, 2-deep register prefetch; A-operand bf16-HI ONLY (R14:
//   dropped lo term -- halves convert VALU + stream MFMAs; error budget
//   0.5 -> ~0.7 of 1.82 threshold).
// Phase B (epilogue, per-wave): G1 -> G3 -> G4 -> leaky(fo + mas_w) -> out.
// Weight fragments from L2-hot ws tables.
// ---------------------------------------------------------------------------
__global__ __launch_bounds__(256, 3) void gfused(
        const float* __restrict__ feat2, const int* __restrict__ adj,
        const float* __restrict__ feat0, const int* __restrict__ bidx,
        const float* __restrict__ scal, const bf16x8* __restrict__ hf,
        const bf16x8* __restrict__ gW1f, const bf16x8* __restrict__ gW2f,
        const bf16x8* __restrict__ gWtH, const bf16x8* __restrict__ gWtL,
        const bf16x8* __restrict__ gO1H, const bf16x8* __restrict__ gO1L,
        const float* __restrict__ w0b1, const float* __restrict__ w0b2,
        const float* __restrict__ omb1, const float* __restrict__ om2v,
        const float* __restrict__ omb2,
        float* __restrict__ out) {
    __shared__ char tile[32768];              // 8 KB per wave
    const int t = threadIdx.x;
    const int w = t >> 6, l = t & 63;
    const int c = l & 15, g = l >> 4;
    const int r16 = blockIdx.x * 4 + w;       // 16-row unit id
    const int li = r16 >> 7;
    const int bi = bidx[li];
    float ke = scal[0], ce = scal[1];
    asm volatile("" : "+v"(ke), "+v"(ce));    // VGPR-pin (constant-bus limit)
    const long long rowg = (long long)bi * O_ + ((r16 & 127) * 16);
    const float* f2base = feat2 + rowg * M_;
    const int*   adb    = adj   + rowg * M_;
    const bf16x8* hfb = hf + li * 4096;
    char* wbase = tile + w * 8192;

    const int rl = l >> 4, q = l & 15;
    const float* gF0 = f2base + (0 * 4 + rl) * 512 + q * 4;
    const float* gF1 = f2base + (1 * 4 + rl) * 512 + q * 4;
    const float* gF2 = f2base + (2 * 4 + rl) * 512 + q * 4;
    const float* gF3 = f2base + (3 * 4 + rl) * 512 + q * 4;
    const int* gA0 = adb + (0 * 4 + rl) * 512 + q * 4;
    const int* gA1 = adb + (1 * 4 + rl) * 512 + q * 4;
    const int* gA2 = adb + (2 * 4 + rl) * 512 + q * 4;
    const int* gA3 = adb + (3 * 4 + rl) * 512 + q * 4;
    char* wp0 = wbase + (((0 * 4 + rl) * 16 + (q ^ ((0 * 4 + rl) & 7))) * 16);
    char* wp1 = wbase + (((1 * 4 + rl) * 16 + (q ^ ((1 * 4 + rl) & 7))) * 16);
    char* wp2 = wbase + (((2 * 4 + rl) * 16 + (q ^ ((2 * 4 + rl) & 7))) * 16);
    char* wp3 = wbase + (((3 * 4 + rl) * 16 + (q ^ ((3 * 4 + rl) & 7))) * 16);
    const int s7 = c & 7;
    const char* rd0 = wbase + ((c * 16 + ((g * 2 + 0) ^ s7)) * 16);
    const char* rd1 = wbase + ((c * 16 + ((g * 2 + 1) ^ s7)) * 16);

    f32x4 acc0 = {0.f, 0.f, 0.f, 0.f}, acc1 = {0.f, 0.f, 0.f, 0.f};
    f32x4 acc2 = {0.f, 0.f, 0.f, 0.f}, acc3 = {0.f, 0.f, 0.f, 0.f};

    float4 fA0, fA1, fA2, fA3, fB0, fB1, fB2, fB3;
    int4   aA0, aA1, aA2, aA3, aB0, aB1, aB2, aB3;

#define G2LOADG(ch, F0, F1, F2, F3, A0, A1, A2, A3) {                   \
    F0 = *(const float4*)(gF0 + (ch) * 64);                             \
    F1 = *(const float4*)(gF1 + (ch) * 64);                             \
    F2 = *(const float4*)(gF2 + (ch) * 64);                             \
    F3 = *(const float4*)(gF3 + (ch) * 64);                             \
    A0 = *(const int4*)(gA0 + (ch) * 64);                               \
    A1 = *(const int4*)(gA1 + (ch) * 64);                               \
    A2 = *(const int4*)(gA2 + (ch) * 64);                               \
    A3 = *(const int4*)(gA3 + (ch) * 64); }

#define G2STORE_LDS(F0, F1, F2, F3, A0, A1, A2, A3) {                   \
    *(float4*)wp0 = F0; *(float4*)wp1 = F1;                             \
    *(float4*)wp2 = F2; *(float4*)wp3 = F3;                             \
    *(int4*)(wp0 + 4096) = A0; *(int4*)(wp1 + 4096) = A1;               \
    *(int4*)(wp2 + 4096) = A2; *(int4*)(wp3 + 4096) = A3; }

#define G2CV4(e4, m4, ah, o) {                                          \
    ah[o + 0] = (short)f2b((m4.x == 1) ? fmaf(e4.x, ke, ce) : 0.f);     \
    ah[o + 1] = (short)f2b((m4.y == 1) ? fmaf(e4.y, ke, ce) : 0.f);     \
    ah[o + 2] = (short)f2b((m4.z == 1) ? fmaf(e4.z, ke, ce) : 0.f);     \
    ah[o + 3] = (short)f2b((m4.w == 1) ? fmaf(e4.w, ke, ce) : 0.f); }

#define G2KS(ksg, off) {                                                \
    float4 e0 = *(const float4*)(rd0 + (off));                          \
    float4 e1 = *(const float4*)(rd1 + (off));                          \
    int4   m0 = *(const int4*)(rd0 + 4096 + (off));                     \
    int4   m1 = *(const int4*)(rd1 + 4096 + (off));                     \
    bf16x8 bb0 = hfb[(0 * 16 + (ksg)) * 64 + l];                        \
    bf16x8 bb1 = hfb[(1 * 16 + (ksg)) * 64 + l];                        \
    bf16x8 bb2 = hfb[(2 * 16 + (ksg)) * 64 + l];                        \
    bf16x8 bb3 = hfb[(3 * 16 + (ksg)) * 64 + l];                        \
    bf16x8 ah;                                                          \
    G2CV4(e0, m0, ah, 0);                                               \
    G2CV4(e1, m1, ah, 4);                                               \
    acc0 = __builtin_amdgcn_mfma_f32_16x16x32_bf16(ah, bb0, acc0, 0, 0, 0); \
    acc1 = __builtin_amdgcn_mfma_f32_16x16x32_bf16(ah, bb1, acc1, 0, 0, 0); \
    acc2 = __builtin_amdgcn_mfma_f32_16x16x32_bf16(ah, bb2, acc2, 0, 0, 0); \
    acc3 = __builtin_amdgcn_mfma_f32_16x16x32_bf16(ah, bb3, acc3, 0, 0, 0); }

    // ---- Phase A: stream loop, 2-deep register prefetch ----
    G2LOADG(0, fA0, fA1, fA2, fA3, aA0, aA1, aA2, aA3);
    G2LOADG(1, fB0, fB1, fB2, fB3, aB0, aB1, aB2, aB3);
    #pragma unroll
    for (int ip = 0; ip < 4; ++ip) {
        G2STORE_LDS(fA0, fA1, fA2, fA3, aA0, aA1, aA2, aA3);
        if (ip < 3) G2LOADG(2 * ip + 2, fA0, fA1, fA2, fA3, aA0, aA1, aA2, aA3);
        G2KS(4 * ip + 0, 0);
        G2KS(4 * ip + 1, 128);
        G2STORE_LDS(fB0, fB1, fB2, fB3, aB0, aB1, aB2, aB3);
        if (ip < 3) G2LOADG(2 * ip + 3, fB0, fB1, fB2, fB3, aB0, aB1, aB2, aB3);
        G2KS(4 * ip + 2, 0);
        G2KS(4 * ip + 3, 128);
    }

    // ---- Phase B: per-wave epilogue (scratch = wave tile, seq. aliasing) ----
    char* Sw = wbase;
    const long long outbase = (long long)li * O_ + ((r16 & 127) * 16);

    // G1: feat_opt = elu(feat0@W1+b1)@W2
    f32x4 fo[2];
    {
        const float* f0b = feat0 + rowg * FIN;
        f32x4 h1[8];
        #pragma unroll
        for (int nf = 0; nf < 8; ++nf) h1[nf] = (f32x4){0.f, 0.f, 0.f, 0.f};
        #pragma unroll
        for (int ks = 0; ks < 2; ++ks) {
            const float* ap = f0b + c * FIN + ks * 32 + g * 8;
            float4 x0 = *(const float4*)ap;
            float4 x1 = *(const float4*)(ap + 4);
            bf16x8 a;
            a[0] = (short)f2b(x0.x); a[1] = (short)f2b(x0.y);
            a[2] = (short)f2b(x0.z); a[3] = (short)f2b(x0.w);
            a[4] = (short)f2b(x1.x); a[5] = (short)f2b(x1.y);
            a[6] = (short)f2b(x1.z); a[7] = (short)f2b(x1.w);
            #pragma unroll
            for (int nf = 0; nf < 8; ++nf)
                h1[nf] = __builtin_amdgcn_mfma_f32_16x16x32_bf16(
                    a, gW1f[(nf * 2 + ks) * 64 + l], h1[nf], 0, 0, 0);
        }
        #pragma unroll
        for (int nf = 0; nf < 8; ++nf) {
            float bb = w0b1[nf * 16 + c];
            #pragma unroll
            for (int reg = 0; reg < 4; ++reg) {
                int row = g * 4 + reg;
                *(unsigned short*)(Sw + row * 272 + (nf * 16 + c) * 2) =
                    f2b(elu_f(h1[nf][reg] + bb));
            }
        }
        fo[0] = (f32x4){0.f, 0.f, 0.f, 0.f};
        fo[1] = (f32x4){0.f, 0.f, 0.f, 0.f};
        #pragma unroll
        for (int ks = 0; ks < 4; ++ks) {
            bf16x8 a = *(const bf16x8*)(Sw + c * 272 + ks * 64 + g * 16);
            #pragma unroll
            for (int nf2 = 0; nf2 < 2; ++nf2)
                fo[nf2] = __builtin_amdgcn_mfma_f32_16x16x32_bf16(
                    a, gW2f[(nf2 * 4 + ks) * 64 + l], fo[nf2], 0, 0, 0);
        }
    }

    // G3: typed = agg @ Wt  (acc -> hi/lo scratch transpose -> MFMA)
    f32x4 ty[6];
    {
        char* aggH = Sw;
        char* aggL = Sw + 2304;
        #pragma unroll
        for (int reg = 0; reg < 4; ++reg) {
            int row = g * 4 + reg;
            short h, lo;
            splitw(acc0[reg], h, lo);
            *(short*)(aggH + row * 144 + (0 * 16 + c) * 2) = h;
            *(short*)(aggL + row * 144 + (0 * 16 + c) * 2) = lo;
            splitw(acc1[reg], h, lo);
            *(short*)(aggH + row * 144 + (1 * 16 + c) * 2) = h;
            *(short*)(aggL + row * 144 + (1 * 16 + c) * 2) = lo;
            splitw(acc2[reg], h, lo);
            *(short*)(aggH + row * 144 + (2 * 16 + c) * 2) = h;
            *(short*)(aggL + row * 144 + (2 * 16 + c) * 2) = lo;
            splitw(acc3[reg], h, lo);
            *(short*)(aggH + row * 144 + (3 * 16 + c) * 2) = h;
            *(short*)(aggL + row * 144 + (3 * 16 + c) * 2) = lo;
        }
        #pragma unroll
        for (int nf = 0; nf < 6; ++nf) ty[nf] = (f32x4){0.f, 0.f, 0.f, 0.f};
        #pragma unroll
        for (int ks = 0; ks < 2; ++ks) {
            bf16x8 aH = *(const bf16x8*)(aggH + c * 144 + ks * 64 + g * 16);
            bf16x8 aL = *(const bf16x8*)(aggL + c * 144 + ks * 64 + g * 16);
            #pragma unroll
            for (int nf = 0; nf < 6; ++nf) {
                bf16x8 bH = gWtH[(nf * 2 + ks) * 64 + l];
                bf16x8 bL = gWtL[(nf * 2 + ks) * 64 + l];
                ty[nf] = __builtin_amdgcn_mfma_f32_16x16x32_bf16(aH, bH, ty[nf], 0, 0, 0);
                ty[nf] = __builtin_amdgcn_mfma_f32_16x16x32_bf16(aL, bH, ty[nf], 0, 0, 0);
                ty[nf] = __builtin_amdgcn_mfma_f32_16x16x32_bf16(aH, bL, ty[nf], 0, 0, 0);
            }
        }
    }

    // G4: mas_w = elu(typed@om1+b1)@om2 + b2  (ty -> hi/lo scratch -> MFMA)
    float p[4] = {0.f, 0.f, 0.f, 0.f};
    {
        char* tyH = Sw;
        char* tyL = Sw + 3328;
        #pragma unroll
        for (int nf = 0; nf < 6; ++nf)
            #pragma unroll
            for (int reg = 0; reg < 4; ++reg) {
                int row = g * 4 + reg;
                short h, lo; splitw(ty[nf][reg], h, lo);
                *(short*)(tyH + row * 208 + (nf * 16 + c) * 2) = h;
                *(short*)(tyL + row * 208 + (nf * 16 + c) * 2) = lo;
            }
        f32x4 h2[8];
        #pragma unroll
        for (int nf = 0; nf < 8; ++nf) h2[nf] = (f32x4){0.f, 0.f, 0.f, 0.f};
        #pragma unroll
        for (int ks = 0; ks < 3; ++ks) {
            bf16x8 aH = *(const bf16x8*)(tyH + c * 208 + ks * 64 + g * 16);
            bf16x8 aL = *(const bf16x8*)(tyL + c * 208 + ks * 64 + g * 16);
            #pragma unroll
            for (int nf = 0; nf < 8; ++nf) {
                bf16x8 bH = gO1H[(nf * 3 + ks) * 64 + l];
                bf16x8 bL = gO1L[(nf * 3 + ks) * 64 + l];
                h2[nf] = __builtin_amdgcn_mfma_f32_16x16x32_bf16(aH, bH, h2[nf], 0, 0, 0);
                h2[nf] = __builtin_amdgcn_mfma_f32_16x16x32_bf16(aL, bH, h2[nf], 0, 0, 0);
                h2[nf] = __builtin_amdgcn_mfma_f32_16x16x32_bf16(aH, bL, h2[nf], 0, 0, 0);
            }
        }
        #pragma unroll
        for (int nf = 0; nf < 8; ++nf) {
            float o2 = om2v[nf * 16 + c];
            float bb = omb1[nf * 16 + c];
            #pragma unroll
            for (int reg = 0; reg < 4; ++reg)
                p[reg] += elu_f(h2[nf][reg] + bb) * o2;
        }
        const float ob2 = omb2[0];
        #pragma unroll
        for (int reg = 0; reg < 4; ++reg) {
            #pragma unroll
            for (int off = 1; off < 16; off <<= 1)
                p[reg] += __shfl_xor(p[reg], off, 64);
            p[reg] += ob2;
        }
    }

    // epilogue: out = leaky_relu(feat_opt + b2 + mas_w)
    #pragma unroll
    for (int nf2 = 0; nf2 < 2; ++nf2) {
        float b2v = w0b2[nf2 * 16 + c];
        #pragma unroll
        for (int reg = 0; reg < 4; ++reg) {
            long long orow = outbase + g * 4 + reg;
            float val = fo[nf2][reg] + b2v + p[reg];
            val = val >= 0.f ? val : 0.2f * val;
            out[orow * DOUT + nf2 * 16 + c] = val;
        }
    }
#undef G2LOADG
#undef G2STORE_LDS
#undef G2CV4
#undef G2KS
}

// ---------------------------------------------------------------------------
extern "C" void kernel_launch(void* const* d_in, const int* in_sizes, int n_in,
                              void* d_out, int out_size, void* d_ws, size_t ws_size,
                              hipStream_t stream) {
    const float* feat0 = (const float*)d_in[0];
    const float* feat1 = (const float*)d_in[1];
    const float* feat2 = (const float*)d_in[2];
    const int*   adj   = (const int*)d_in[3];
    const int*   bidx  = (const int*)d_in[4];
    const float* w0_w1 = (const float*)d_in[5];
    const float* w0_b1 = (const float*)d_in[6];
    const float* w0_w2 = (const float*)d_in[7];
    const float* w0_b2 = (const float*)d_in[8];
    const float* v     = (const float*)d_in[9];
    const float* coeff = (const float*)d_in[10];
    const float* e_w1  = (const float*)d_in[11];
    const float* e_b1  = (const float*)d_in[12];
    const float* e_w2  = (const float*)d_in[13];
    const float* e_b2  = (const float*)d_in[14];
    const float* om_w1 = (const float*)d_in[15];
    const float* om_b1 = (const float*)d_in[16];
    const float* om_w2 = (const float*)d_in[17];
    const float* om_b2 = (const float*)d_in[18];
    float* out = (float*)d_out;
    char*  wsb = (char*)d_ws;

    const int bsel = in_sizes[4];              // 32

    float*  ws_scal = (float*)wsb;                    // 64 B
    bf16x8* ws_w1f  = (bf16x8*)(wsb + 4096);          // 16 KB
    bf16x8* ws_w2f  = (bf16x8*)(wsb + 20480);         // 8 KB
    bf16x8* ws_wth  = (bf16x8*)(wsb + 28672);         // 12 KB
    bf16x8* ws_wtl  = (bf16x8*)(wsb + 40960);         // 12 KB
    bf16x8* ws_o1h  = (bf16x8*)(wsb + 53248);         // 24 KB
    bf16x8* ws_o1l  = (bf16x8*)(wsb + 77824);         // 24 KB
    bf16x8* ws_hf   = (bf16x8*)(wsb + 131072);        // 2 MB

    prep<<<15 + bsel * 4, 256, 0, stream>>>(e_w1, e_b1, e_w2, e_b2, coeff, v,
                                            w0_w1, w0_w2, om_w1, feat1, bidx,
                                            ws_scal, ws_w1f, ws_w2f,
                                            ws_wth, ws_wtl, ws_o1h, ws_o1l,
                                            ws_hf);
    gfused<<<bsel * 32, 256, 0, stream>>>(feat2, adj, feat0, bidx,
                                          ws_scal, ws_hf,
                                          ws_w1f, ws_w2f, ws_wth, ws_wtl,
                                          ws_o1h, ws_o1l,
                                          w0_b1, w0_b2, om_b1, om_w2, om_b2,
                                          out);
}

// Round 15
// 68.709 us; speedup vs baseline: 1.0705x; 1.0705x over previous
//
#include <hip/hip_runtime.h>

#define O_ 2048
#define M_ 512
#define FIN 64
#define FMAS 64
#define DOUT 32
#define H_ 128
#define TD 96
#define NB_ 3

typedef __attribute__((ext_vector_type(4))) float f32x4;
typedef __attribute__((ext_vector_type(8))) short bf16x8;

__device__ __forceinline__ float elu_f(float x) {
    return x > 0.f ? x : (__expf(x) - 1.f);
}
__device__ __forceinline__ unsigned short f2b(float x) {
    union { float f; unsigned u; } uu; uu.f = x;
    unsigned r = uu.u + 0x7fffu + ((uu.u >> 16) & 1u);
    return (unsigned short)(r >> 16);
}
__device__ __forceinline__ float b2f(unsigned short s) {
    union { float f; unsigned u; } uu; uu.u = ((unsigned)s) << 16;
    return uu.f;
}
__device__ __forceinline__ void splitw(float x, short& h, short& lo) {
    unsigned u = __float_as_uint(x);
    unsigned short hi = (unsigned short)(u >> 16);
    float rem = x - b2f(hi);
    h = (short)hi;
    lo = (short)(unsigned short)(__float_as_uint(rem) >> 16);
}

// ---------------------------------------------------------------------------
// PREP (143 blocks): blocks 0..14 = weight fragment tables + scalars;
// blocks 15..142 = per-li bf16 H fragment tables (khf).
// ---------------------------------------------------------------------------
__global__ __launch_bounds__(256) void prep(
        const float* __restrict__ e_w1, const float* __restrict__ e_b1,
        const float* __restrict__ e_w2, const float* __restrict__ e_b2,
        const float* __restrict__ coeff, const float* __restrict__ v,
        const float* __restrict__ w0w1, const float* __restrict__ w0w2,
        const float* __restrict__ om1, const float* __restrict__ hmas,
        const int* __restrict__ bidx,
        float* __restrict__ ws_scal,
        bf16x8* __restrict__ w1f, bf16x8* __restrict__ w2f,
        bf16x8* __restrict__ wth, bf16x8* __restrict__ wtl,
        bf16x8* __restrict__ o1h, bf16x8* __restrict__ o1l,
        bf16x8* __restrict__ hf) {
    const int t = threadIdx.x;
    if (blockIdx.x < 15) {
        __shared__ float r1[128], r2[128];
        if (t < 128) { r1[t] = e_w1[t] * e_w2[t]; r2[t] = e_b1[t] * e_w2[t]; }
        __syncthreads();
        for (int s = 64; s > 0; s >>= 1) {
            if (t < s) { r1[t] += r1[t + s]; r2[t] += r2[t + s]; }
            __syncthreads();
        }
        if (blockIdx.x == 0 && t == 0) {
            ws_scal[0] = r1[0];
            ws_scal[1] = r2[0] + e_b2[0];
        }
        const int e = blockIdx.x * 256 + t;       // [0, 3840)
        const int le = e & 63, cc = le & 15, gg = le >> 4;
        if (e < 1024) {
            int nf = e >> 7, ks = (e >> 6) & 1;
            bf16x8 vv;
            #pragma unroll
            for (int j = 0; j < 8; ++j)
                vv[j] = (short)f2b(w0w1[(ks * 32 + gg * 8 + j) * H_ + nf * 16 + cc]);
            w1f[e] = vv;
        } else if (e < 1536) {
            int e2 = e - 1024;
            int nf = e2 >> 8, ks = (e2 >> 6) & 3;
            bf16x8 vv;
            #pragma unroll
            for (int j = 0; j < 8; ++j)
                vv[j] = (short)f2b(w0w2[(ks * 32 + gg * 8 + j) * DOUT + nf * 16 + cc]);
            w2f[e2] = vv;
        } else if (e < 2304) {
            int e3 = e - 1536;
            int nf = e3 >> 7, ks = (e3 >> 6) & 1;
            bf16x8 vh, vl;
            #pragma unroll
            for (int j = 0; j < 8; ++j) {
                int row = ks * 32 + gg * 8 + j;
                int col = nf * 16 + cc;
                int tt = col >> 5, ee = col & 31;
                float s = 0.f;
                #pragma unroll
                for (int nb = 0; nb < NB_; ++nb)
                    s += coeff[tt * NB_ + nb] * v[(nb * FMAS + row) * DOUT + ee];
                short h, lo; splitw(s, h, lo);
                vh[j] = h; vl[j] = lo;
            }
            wth[e3] = vh; wtl[e3] = vl;
        } else if (e < 3840) {
            int e4 = e - 2304;
            int nf = e4 / 192, r = e4 % 192, ks = r >> 6;
            bf16x8 vh, vl;
            #pragma unroll
            for (int j = 0; j < 8; ++j) {
                float vv = om1[(ks * 32 + gg * 8 + j) * H_ + nf * 16 + cc];
                short h, lo; splitw(vv, h, lo);
                vh[j] = h; vl[j] = lo;
            }
            o1h[e4] = vh; o1l[e4] = vl;
        }
    } else {
        const int b2 = blockIdx.x - 15;
        const int li = b2 >> 2;
        const int part = b2 & 3;
        const int bi = bidx[li];
        const float* hb = hmas + (long long)bi * M_ * FMAS;
        bf16x8* dst = hf + li * 4096;
        #pragma unroll
        for (int j4 = 0; j4 < 4; ++j4) {
            int e = part * 1024 + j4 * 256 + t;
            int ft = e >> 10, ks = (e >> 6) & 15, le = e & 63;
            int cc = le & 15, gg = le >> 4;
            const float* src = hb + (ks * 32 + gg * 8) * FMAS + ft * 16 + cc;
            bf16x8 vv;
            #pragma unroll
            for (int j = 0; j < 8; ++j) vv[j] = (short)f2b(src[j * FMAS]);
            dst[e] = vv;
        }
    }
}

// ---------------------------------------------------------------------------
// GFUSED (R13 stream restored, occupancy 3->4 blocks/CU): per wave = 16
// complete output rows; no barriers anywhere.
// Phase A (stream): agg = (mask*(ke*feat2+ce)) @ H -- LDS-staged A-tile,
//   XOR-swizzled, 2-deep register prefetch, A split hi/lo (R14's hi-only
//   regressed: that work was latency-hidden and helped scheduling).
// Phase B (epilogue, per-wave): G1 -> G3 -> G4 -> leaky(fo+mas_w) -> out.
// Grid 1024 = 256 CU x 4 blocks exactly -> single dispatch round, no tail
// (R13's 3/CU left a 256-block tail at 1/3 utilization ~ the 20us slack).
// LDS 32KB x 4 = 128KB <= 160KB.
// ---------------------------------------------------------------------------
__global__ __launch_bounds__(256, 4) void gfused(
        const float* __restrict__ feat2, const int* __restrict__ adj,
        const float* __restrict__ feat0, const int* __restrict__ bidx,
        const float* __restrict__ scal, const bf16x8* __restrict__ hf,
        const bf16x8* __restrict__ gW1f, const bf16x8* __restrict__ gW2f,
        const bf16x8* __restrict__ gWtH, const bf16x8* __restrict__ gWtL,
        const bf16x8* __restrict__ gO1H, const bf16x8* __restrict__ gO1L,
        const float* __restrict__ w0b1, const float* __restrict__ w0b2,
        const float* __restrict__ omb1, const float* __restrict__ om2v,
        const float* __restrict__ omb2,
        float* __restrict__ out) {
    __shared__ char tile[32768];              // 8 KB per wave
    const int t = threadIdx.x;
    const int w = t >> 6, l = t & 63;
    const int c = l & 15, g = l >> 4;
    const int r16 = blockIdx.x * 4 + w;       // 16-row unit id
    const int li = r16 >> 7;
    const int bi = bidx[li];
    float ke = scal[0], ce = scal[1];
    asm volatile("" : "+v"(ke), "+v"(ce));    // VGPR-pin (constant-bus limit)
    const long long rowg = (long long)bi * O_ + ((r16 & 127) * 16);
    const float* f2base = feat2 + rowg * M_;
    const int*   adb    = adj   + rowg * M_;
    const bf16x8* hfb = hf + li * 4096;
    char* wbase = tile + w * 8192;

    const int rl = l >> 4, q = l & 15;
    const float* gF0 = f2base + (0 * 4 + rl) * 512 + q * 4;
    const float* gF1 = f2base + (1 * 4 + rl) * 512 + q * 4;
    const float* gF2 = f2base + (2 * 4 + rl) * 512 + q * 4;
    const float* gF3 = f2base + (3 * 4 + rl) * 512 + q * 4;
    const int* gA0 = adb + (0 * 4 + rl) * 512 + q * 4;
    const int* gA1 = adb + (1 * 4 + rl) * 512 + q * 4;
    const int* gA2 = adb + (2 * 4 + rl) * 512 + q * 4;
    const int* gA3 = adb + (3 * 4 + rl) * 512 + q * 4;
    char* wp0 = wbase + (((0 * 4 + rl) * 16 + (q ^ ((0 * 4 + rl) & 7))) * 16);
    char* wp1 = wbase + (((1 * 4 + rl) * 16 + (q ^ ((1 * 4 + rl) & 7))) * 16);
    char* wp2 = wbase + (((2 * 4 + rl) * 16 + (q ^ ((2 * 4 + rl) & 7))) * 16);
    char* wp3 = wbase + (((3 * 4 + rl) * 16 + (q ^ ((3 * 4 + rl) & 7))) * 16);
    const int s7 = c & 7;
    const char* rd0 = wbase + ((c * 16 + ((g * 2 + 0) ^ s7)) * 16);
    const char* rd1 = wbase + ((c * 16 + ((g * 2 + 1) ^ s7)) * 16);

    f32x4 acc0 = {0.f, 0.f, 0.f, 0.f}, acc1 = {0.f, 0.f, 0.f, 0.f};
    f32x4 acc2 = {0.f, 0.f, 0.f, 0.f}, acc3 = {0.f, 0.f, 0.f, 0.f};

    float4 fA0, fA1, fA2, fA3, fB0, fB1, fB2, fB3;
    int4   aA0, aA1, aA2, aA3, aB0, aB1, aB2, aB3;

#define G2LOADG(ch, F0, F1, F2, F3, A0, A1, A2, A3) {                   \
    F0 = *(const float4*)(gF0 + (ch) * 64);                             \
    F1 = *(const float4*)(gF1 + (ch) * 64);                             \
    F2 = *(const float4*)(gF2 + (ch) * 64);                             \
    F3 = *(const float4*)(gF3 + (ch) * 64);                             \
    A0 = *(const int4*)(gA0 + (ch) * 64);                               \
    A1 = *(const int4*)(gA1 + (ch) * 64);                               \
    A2 = *(const int4*)(gA2 + (ch) * 64);                               \
    A3 = *(const int4*)(gA3 + (ch) * 64); }

#define G2STORE_LDS(F0, F1, F2, F3, A0, A1, A2, A3) {                   \
    *(float4*)wp0 = F0; *(float4*)wp1 = F1;                             \
    *(float4*)wp2 = F2; *(float4*)wp3 = F3;                             \
    *(int4*)(wp0 + 4096) = A0; *(int4*)(wp1 + 4096) = A1;               \
    *(int4*)(wp2 + 4096) = A2; *(int4*)(wp3 + 4096) = A3; }

#define G2CV4(e4, m4, ah, al_, o) {                                     \
    short h_, l_;                                                       \
    splitw((m4.x == 1) ? fmaf(e4.x, ke, ce) : 0.f, h_, l_);             \
    ah[o + 0] = h_; al_[o + 0] = l_;                                    \
    splitw((m4.y == 1) ? fmaf(e4.y, ke, ce) : 0.f, h_, l_);             \
    ah[o + 1] = h_; al_[o + 1] = l_;                                    \
    splitw((m4.z == 1) ? fmaf(e4.z, ke, ce) : 0.f, h_, l_);             \
    ah[o + 2] = h_; al_[o + 2] = l_;                                    \
    splitw((m4.w == 1) ? fmaf(e4.w, ke, ce) : 0.f, h_, l_);             \
    ah[o + 3] = h_; al_[o + 3] = l_; }

#define G2KS(ksg, off) {                                                \
    float4 e0 = *(const float4*)(rd0 + (off));                          \
    float4 e1 = *(const float4*)(rd1 + (off));                          \
    int4   m0 = *(const int4*)(rd0 + 4096 + (off));                     \
    int4   m1 = *(const int4*)(rd1 + 4096 + (off));                     \
    bf16x8 bb0 = hfb[(0 * 16 + (ksg)) * 64 + l];                        \
    bf16x8 bb1 = hfb[(1 * 16 + (ksg)) * 64 + l];                        \
    bf16x8 bb2 = hfb[(2 * 16 + (ksg)) * 64 + l];                        \
    bf16x8 bb3 = hfb[(3 * 16 + (ksg)) * 64 + l];                        \
    bf16x8 ah, al_;                                                     \
    G2CV4(e0, m0, ah, al_, 0);                                          \
    G2CV4(e1, m1, ah, al_, 4);                                          \
    acc0 = __builtin_amdgcn_mfma_f32_16x16x32_bf16(ah, bb0, acc0, 0, 0, 0); \
    acc0 = __builtin_amdgcn_mfma_f32_16x16x32_bf16(al_, bb0, acc0, 0, 0, 0); \
    acc1 = __builtin_amdgcn_mfma_f32_16x16x32_bf16(ah, bb1, acc1, 0, 0, 0); \
    acc1 = __builtin_amdgcn_mfma_f32_16x16x32_bf16(al_, bb1, acc1, 0, 0, 0); \
    acc2 = __builtin_amdgcn_mfma_f32_16x16x32_bf16(ah, bb2, acc2, 0, 0, 0); \
    acc2 = __builtin_amdgcn_mfma_f32_16x16x32_bf16(al_, bb2, acc2, 0, 0, 0); \
    acc3 = __builtin_amdgcn_mfma_f32_16x16x32_bf16(ah, bb3, acc3, 0, 0, 0); \
    acc3 = __builtin_amdgcn_mfma_f32_16x16x32_bf16(al_, bb3, acc3, 0, 0, 0); }

    // ---- Phase A: stream loop, 2-deep register prefetch ----
    G2LOADG(0, fA0, fA1, fA2, fA3, aA0, aA1, aA2, aA3);
    G2LOADG(1, fB0, fB1, fB2, fB3, aB0, aB1, aB2, aB3);
    #pragma unroll
    for (int ip = 0; ip < 4; ++ip) {
        G2STORE_LDS(fA0, fA1, fA2, fA3, aA0, aA1, aA2, aA3);
        if (ip < 3) G2LOADG(2 * ip + 2, fA0, fA1, fA2, fA3, aA0, aA1, aA2, aA3);
        G2KS(4 * ip + 0, 0);
        G2KS(4 * ip + 1, 128);
        G2STORE_LDS(fB0, fB1, fB2, fB3, aB0, aB1, aB2, aB3);
        if (ip < 3) G2LOADG(2 * ip + 3, fB0, fB1, fB2, fB3, aB0, aB1, aB2, aB3);
        G2KS(4 * ip + 2, 0);
        G2KS(4 * ip + 3, 128);
    }

    // ---- Phase B: per-wave epilogue (scratch = wave tile, seq. aliasing) ----
    char* Sw = wbase;
    const long long outbase = (long long)li * O_ + ((r16 & 127) * 16);

    // G1: feat_opt = elu(feat0@W1+b1)@W2
    f32x4 fo[2];
    {
        const float* f0b = feat0 + rowg * FIN;
        f32x4 h1[8];
        #pragma unroll
        for (int nf = 0; nf < 8; ++nf) h1[nf] = (f32x4){0.f, 0.f, 0.f, 0.f};
        #pragma unroll
        for (int ks = 0; ks < 2; ++ks) {
            const float* ap = f0b + c * FIN + ks * 32 + g * 8;
            float4 x0 = *(const float4*)ap;
            float4 x1 = *(const float4*)(ap + 4);
            bf16x8 a;
            a[0] = (short)f2b(x0.x); a[1] = (short)f2b(x0.y);
            a[2] = (short)f2b(x0.z); a[3] = (short)f2b(x0.w);
            a[4] = (short)f2b(x1.x); a[5] = (short)f2b(x1.y);
            a[6] = (short)f2b(x1.z); a[7] = (short)f2b(x1.w);
            #pragma unroll
            for (int nf = 0; nf < 8; ++nf)
                h1[nf] = __builtin_amdgcn_mfma_f32_16x16x32_bf16(
                    a, gW1f[(nf * 2 + ks) * 64 + l], h1[nf], 0, 0, 0);
        }
        #pragma unroll
        for (int nf = 0; nf < 8; ++nf) {
            float bb = w0b1[nf * 16 + c];
            #pragma unroll
            for (int reg = 0; reg < 4; ++reg) {
                int row = g * 4 + reg;
                *(unsigned short*)(Sw + row * 272 + (nf * 16 + c) * 2) =
                    f2b(elu_f(h1[nf][reg] + bb));
            }
        }
        fo[0] = (f32x4){0.f, 0.f, 0.f, 0.f};
        fo[1] = (f32x4){0.f, 0.f, 0.f, 0.f};
        #pragma unroll
        for (int ks = 0; ks < 4; ++ks) {
            bf16x8 a = *(const bf16x8*)(Sw + c * 272 + ks * 64 + g * 16);
            #pragma unroll
            for (int nf2 = 0; nf2 < 2; ++nf2)
                fo[nf2] = __builtin_amdgcn_mfma_f32_16x16x32_bf16(
                    a, gW2f[(nf2 * 4 + ks) * 64 + l], fo[nf2], 0, 0, 0);
        }
    }

    // G3: typed = agg @ Wt  (acc -> hi/lo scratch transpose -> MFMA)
    f32x4 ty[6];
    {
        char* aggH = Sw;
        char* aggL = Sw + 2304;
        #pragma unroll
        for (int reg = 0; reg < 4; ++reg) {
            int row = g * 4 + reg;
            short h, lo;
            splitw(acc0[reg], h, lo);
            *(short*)(aggH + row * 144 + (0 * 16 + c) * 2) = h;
            *(short*)(aggL + row * 144 + (0 * 16 + c) * 2) = lo;
            splitw(acc1[reg], h, lo);
            *(short*)(aggH + row * 144 + (1 * 16 + c) * 2) = h;
            *(short*)(aggL + row * 144 + (1 * 16 + c) * 2) = lo;
            splitw(acc2[reg], h, lo);
            *(short*)(aggH + row * 144 + (2 * 16 + c) * 2) = h;
            *(short*)(aggL + row * 144 + (2 * 16 + c) * 2) = lo;
            splitw(acc3[reg], h, lo);
            *(short*)(aggH + row * 144 + (3 * 16 + c) * 2) = h;
            *(short*)(aggL + row * 144 + (3 * 16 + c) * 2) = lo;
        }
        #pragma unroll
        for (int nf = 0; nf < 6; ++nf) ty[nf] = (f32x4){0.f, 0.f, 0.f, 0.f};
        #pragma unroll
        for (int ks = 0; ks < 2; ++ks) {
            bf16x8 aH = *(const bf16x8*)(aggH + c * 144 + ks * 64 + g * 16);
            bf16x8 aL = *(const bf16x8*)(aggL + c * 144 + ks * 64 + g * 16);
            #pragma unroll
            for (int nf = 0; nf < 6; ++nf) {
                bf16x8 bH = gWtH[(nf * 2 + ks) * 64 + l];
                bf16x8 bL = gWtL[(nf * 2 + ks) * 64 + l];
                ty[nf] = __builtin_amdgcn_mfma_f32_16x16x32_bf16(aH, bH, ty[nf], 0, 0, 0);
                ty[nf] = __builtin_amdgcn_mfma_f32_16x16x32_bf16(aL, bH, ty[nf], 0, 0, 0);
                ty[nf] = __builtin_amdgcn_mfma_f32_16x16x32_bf16(aH, bL, ty[nf], 0, 0, 0);
            }
        }
    }

    // G4: mas_w = elu(typed@om1+b1)@om2 + b2  (ty -> hi/lo scratch -> MFMA)
    float p[4] = {0.f, 0.f, 0.f, 0.f};
    {
        char* tyH = Sw;
        char* tyL = Sw + 3328;
        #pragma unroll
        for (int nf = 0; nf < 6; ++nf)
            #pragma unroll
            for (int reg = 0; reg < 4; ++reg) {
                int row = g * 4 + reg;
                short h, lo; splitw(ty[nf][reg], h, lo);
                *(short*)(tyH + row * 208 + (nf * 16 + c) * 2) = h;
                *(short*)(tyL + row * 208 + (nf * 16 + c) * 2) = lo;
            }
        f32x4 h2[8];
        #pragma unroll
        for (int nf = 0; nf < 8; ++nf) h2[nf] = (f32x4){0.f, 0.f, 0.f, 0.f};
        #pragma unroll
        for (int ks = 0; ks < 3; ++ks) {
            bf16x8 aH = *(const bf16x8*)(tyH + c * 208 + ks * 64 + g * 16);
            bf16x8 aL = *(const bf16x8*)(tyL + c * 208 + ks * 64 + g * 16);
            #pragma unroll
            for (int nf = 0; nf < 8; ++nf) {
                bf16x8 bH = gO1H[(nf * 3 + ks) * 64 + l];
                bf16x8 bL = gO1L[(nf * 3 + ks) * 64 + l];
                h2[nf] = __builtin_amdgcn_mfma_f32_16x16x32_bf16(aH, bH, h2[nf], 0, 0, 0);
                h2[nf] = __builtin_amdgcn_mfma_f32_16x16x32_bf16(aL, bH, h2[nf], 0, 0, 0);
                h2[nf] = __builtin_amdgcn_mfma_f32_16x16x32_bf16(aH, bL, h2[nf], 0, 0, 0);
            }
        }
        #pragma unroll
        for (int nf = 0; nf < 8; ++nf) {
            float o2 = om2v[nf * 16 + c];
            float bb = omb1[nf * 16 + c];
            #pragma unroll
            for (int reg = 0; reg < 4; ++reg)
                p[reg] += elu_f(h2[nf][reg] + bb) * o2;
        }
        const float ob2 = omb2[0];
        #pragma unroll
        for (int reg = 0; reg < 4; ++reg) {
            #pragma unroll
            for (int off = 1; off < 16; off <<= 1)
                p[reg] += __shfl_xor(p[reg], off, 64);
            p[reg] += ob2;
        }
    }

    // epilogue: out = leaky_relu(feat_opt + b2 + mas_w)
    #pragma unroll
    for (int nf2 = 0; nf2 < 2; ++nf2) {
        float b2v = w0b2[nf2 * 16 + c];
        #pragma unroll
        for (int reg = 0; reg < 4; ++reg) {
            long long orow = outbase + g * 4 + reg;
            float val = fo[nf2][reg] + b2v + p[reg];
            val = val >= 0.f ? val : 0.2f * val;
            out[orow * DOUT + nf2 * 16 + c] = val;
        }
    }
#undef G2LOADG
#undef G2STORE_LDS
#undef G2CV4
#undef G2KS
}

// ---------------------------------------------------------------------------
extern "C" void kernel_launch(void* const* d_in, const int* in_sizes, int n_in,
                              void* d_out, int out_size, void* d_ws, size_t ws_size,
                              hipStream_t stream) {
    const float* feat0 = (const float*)d_in[0];
    const float* feat1 = (const float*)d_in[1];
    const float* feat2 = (const float*)d_in[2];
    const int*   adj   = (const int*)d_in[3];
    const int*   bidx  = (const int*)d_in[4];
    const float* w0_w1 = (const float*)d_in[5];
    const float* w0_b1 = (const float*)d_in[6];
    const float* w0_w2 = (const float*)d_in[7];
    const float* w0_b2 = (const float*)d_in[8];
    const float* v     = (const float*)d_in[9];
    const float* coeff = (const float*)d_in[10];
    const float* e_w1  = (const float*)d_in[11];
    const float* e_b1  = (const float*)d_in[12];
    const float* e_w2  = (const float*)d_in[13];
    const float* e_b2  = (const float*)d_in[14];
    const float* om_w1 = (const float*)d_in[15];
    const float* om_b1 = (const float*)d_in[16];
    const float* om_w2 = (const float*)d_in[17];
    const float* om_b2 = (const float*)d_in[18];
    float* out = (float*)d_out;
    char*  wsb = (char*)d_ws;

    const int bsel = in_sizes[4];              // 32

    float*  ws_scal = (float*)wsb;                    // 64 B
    bf16x8* ws_w1f  = (bf16x8*)(wsb + 4096);          // 16 KB
    bf16x8* ws_w2f  = (bf16x8*)(wsb + 20480);         // 8 KB
    bf16x8* ws_wth  = (bf16x8*)(wsb + 28672);         // 12 KB
    bf16x8* ws_wtl  = (bf16x8*)(wsb + 40960);         // 12 KB
    bf16x8* ws_o1h  = (bf16x8*)(wsb + 53248);         // 24 KB
    bf16x8* ws_o1l  = (bf16x8*)(wsb + 77824);         // 24 KB
    bf16x8* ws_hf   = (bf16x8*)(wsb + 131072);        // 2 MB

    prep<<<15 + bsel * 4, 256, 0, stream>>>(e_w1, e_b1, e_w2, e_b2, coeff, v,
                                            w0_w1, w0_w2, om_w1, feat1, bidx,
                                            ws_scal, ws_w1f, ws_w2f,
                                            ws_wth, ws_wtl, ws_o1h, ws_o1l,
                                            ws_hf);
    gfused<<<bsel * 32, 256, 0, stream>>>(feat2, adj, feat0, bidx,
                                          ws_scal, ws_hf,
                                          ws_w1f, ws_w2f, ws_wth, ws_wtl,
                                          ws_o1h, ws_o1l,
                                          w0_b1, w0_b2, om_b1, om_w2, om_b2,
                                          out);
}

// Round 16
// 65.980 us; speedup vs baseline: 1.1148x; 1.0414x over previous
//
#include <hip/hip_runtime.h>

#define O_ 2048
#define M_ 512
#define FIN 64
#define FMAS 64
#define DOUT 32
#define H_ 128
#define TD 96
#define NB_ 3

typedef __attribute__((ext_vector_type(4))) float f32x4;
typedef __attribute__((ext_vector_type(8))) short bf16x8;

__device__ __forceinline__ float elu_f(float x) {
    return x > 0.f ? x : (__expf(x) - 1.f);
}
__device__ __forceinline__ unsigned short f2b(float x) {
    union { float f; unsigned u; } uu; uu.f = x;
    unsigned r = uu.u + 0x7fffu + ((uu.u >> 16) & 1u);
    return (unsigned short)(r >> 16);
}
__device__ __forceinline__ float b2f(unsigned short s) {
    union { float f; unsigned u; } uu; uu.u = ((unsigned)s) << 16;
    return uu.f;
}
__device__ __forceinline__ void splitw(float x, short& h, short& lo) {
    unsigned u = __float_as_uint(x);
    unsigned short hi = (unsigned short)(u >> 16);
    float rem = x - b2f(hi);
    h = (short)hi;
    lo = (short)(unsigned short)(__float_as_uint(rem) >> 16);
}

// ---------------------------------------------------------------------------
// PREP (143 blocks): blocks 0..14 = weight fragment tables + scalars;
// blocks 15..142 = per-li bf16 H fragment tables (khf).
// ---------------------------------------------------------------------------
__global__ __launch_bounds__(256) void prep(
        const float* __restrict__ e_w1, const float* __restrict__ e_b1,
        const float* __restrict__ e_w2, const float* __restrict__ e_b2,
        const float* __restrict__ coeff, const float* __restrict__ v,
        const float* __restrict__ w0w1, const float* __restrict__ w0w2,
        const float* __restrict__ om1, const float* __restrict__ hmas,
        const int* __restrict__ bidx,
        float* __restrict__ ws_scal,
        bf16x8* __restrict__ w1f, bf16x8* __restrict__ w2f,
        bf16x8* __restrict__ wth, bf16x8* __restrict__ wtl,
        bf16x8* __restrict__ o1h, bf16x8* __restrict__ o1l,
        bf16x8* __restrict__ hf) {
    const int t = threadIdx.x;
    if (blockIdx.x < 15) {
        __shared__ float r1[128], r2[128];
        if (t < 128) { r1[t] = e_w1[t] * e_w2[t]; r2[t] = e_b1[t] * e_w2[t]; }
        __syncthreads();
        for (int s = 64; s > 0; s >>= 1) {
            if (t < s) { r1[t] += r1[t + s]; r2[t] += r2[t + s]; }
            __syncthreads();
        }
        if (blockIdx.x == 0 && t == 0) {
            ws_scal[0] = r1[0];
            ws_scal[1] = r2[0] + e_b2[0];
        }
        const int e = blockIdx.x * 256 + t;       // [0, 3840)
        const int le = e & 63, cc = le & 15, gg = le >> 4;
        if (e < 1024) {
            int nf = e >> 7, ks = (e >> 6) & 1;
            bf16x8 vv;
            #pragma unroll
            for (int j = 0; j < 8; ++j)
                vv[j] = (short)f2b(w0w1[(ks * 32 + gg * 8 + j) * H_ + nf * 16 + cc]);
            w1f[e] = vv;
        } else if (e < 1536) {
            int e2 = e - 1024;
            int nf = e2 >> 8, ks = (e2 >> 6) & 3;
            bf16x8 vv;
            #pragma unroll
            for (int j = 0; j < 8; ++j)
                vv[j] = (short)f2b(w0w2[(ks * 32 + gg * 8 + j) * DOUT + nf * 16 + cc]);
            w2f[e2] = vv;
        } else if (e < 2304) {
            int e3 = e - 1536;
            int nf = e3 >> 7, ks = (e3 >> 6) & 1;
            bf16x8 vh, vl;
            #pragma unroll
            for (int j = 0; j < 8; ++j) {
                int row = ks * 32 + gg * 8 + j;
                int col = nf * 16 + cc;
                int tt = col >> 5, ee = col & 31;
                float s = 0.f;
                #pragma unroll
                for (int nb = 0; nb < NB_; ++nb)
                    s += coeff[tt * NB_ + nb] * v[(nb * FMAS + row) * DOUT + ee];
                short h, lo; splitw(s, h, lo);
                vh[j] = h; vl[j] = lo;
            }
            wth[e3] = vh; wtl[e3] = vl;
        } else if (e < 3840) {
            int e4 = e - 2304;
            int nf = e4 / 192, r = e4 % 192, ks = r >> 6;
            bf16x8 vh, vl;
            #pragma unroll
            for (int j = 0; j < 8; ++j) {
                float vv = om1[(ks * 32 + gg * 8 + j) * H_ + nf * 16 + cc];
                short h, lo; splitw(vv, h, lo);
                vh[j] = h; vl[j] = lo;
            }
            o1h[e4] = vh; o1l[e4] = vl;
        }
    } else {
        const int b2 = blockIdx.x - 15;
        const int li = b2 >> 2;
        const int part = b2 & 3;
        const int bi = bidx[li];
        const float* hb = hmas + (long long)bi * M_ * FMAS;
        bf16x8* dst = hf + li * 4096;
        #pragma unroll
        for (int j4 = 0; j4 < 4; ++j4) {
            int e = part * 1024 + j4 * 256 + t;
            int ft = e >> 10, ks = (e >> 6) & 15, le = e & 63;
            int cc = le & 15, gg = le >> 4;
            const float* src = hb + (ks * 32 + gg * 8) * FMAS + ft * 16 + cc;
            bf16x8 vv;
            #pragma unroll
            for (int j = 0; j < 8; ++j) vv[j] = (short)f2b(src[j * FMAS]);
            dst[e] = vv;
        }
    }
}

// ---------------------------------------------------------------------------
// GFUSED (R13 exact): per wave = 16 complete output rows; no barriers.
// Phase A (stream): agg = (mask*(ke*feat2+ce)) @ H -- LDS-staged A-tile,
//   XOR-swizzled, 2-deep register prefetch, A split hi/lo.
// Phase B (epilogue, per-wave): G1 -> G3 -> G4 -> leaky(fo+mas_w) -> out.
// 3 blocks/CU (R15 measured: 4/CU with the 128-VGPR cap regressed 65.5->68.7;
// R14 measured: hi-only stream regressed 65.5->73.6 -- both reverted).
// ---------------------------------------------------------------------------
__global__ __launch_bounds__(256, 3) void gfused(
        const float* __restrict__ feat2, const int* __restrict__ adj,
        const float* __restrict__ feat0, const int* __restrict__ bidx,
        const float* __restrict__ scal, const bf16x8* __restrict__ hf,
        const bf16x8* __restrict__ gW1f, const bf16x8* __restrict__ gW2f,
        const bf16x8* __restrict__ gWtH, const bf16x8* __restrict__ gWtL,
        const bf16x8* __restrict__ gO1H, const bf16x8* __restrict__ gO1L,
        const float* __restrict__ w0b1, const float* __restrict__ w0b2,
        const float* __restrict__ omb1, const float* __restrict__ om2v,
        const float* __restrict__ omb2,
        float* __restrict__ out) {
    __shared__ char tile[32768];              // 8 KB per wave
    const int t = threadIdx.x;
    const int w = t >> 6, l = t & 63;
    const int c = l & 15, g = l >> 4;
    const int r16 = blockIdx.x * 4 + w;       // 16-row unit id
    const int li = r16 >> 7;
    const int bi = bidx[li];
    float ke = scal[0], ce = scal[1];
    asm volatile("" : "+v"(ke), "+v"(ce));    // VGPR-pin (constant-bus limit)
    const long long rowg = (long long)bi * O_ + ((r16 & 127) * 16);
    const float* f2base = feat2 + rowg * M_;
    const int*   adb    = adj   + rowg * M_;
    const bf16x8* hfb = hf + li * 4096;
    char* wbase = tile + w * 8192;

    const int rl = l >> 4, q = l & 15;
    const float* gF0 = f2base + (0 * 4 + rl) * 512 + q * 4;
    const float* gF1 = f2base + (1 * 4 + rl) * 512 + q * 4;
    const float* gF2 = f2base + (2 * 4 + rl) * 512 + q * 4;
    const float* gF3 = f2base + (3 * 4 + rl) * 512 + q * 4;
    const int* gA0 = adb + (0 * 4 + rl) * 512 + q * 4;
    const int* gA1 = adb + (1 * 4 + rl) * 512 + q * 4;
    const int* gA2 = adb + (2 * 4 + rl) * 512 + q * 4;
    const int* gA3 = adb + (3 * 4 + rl) * 512 + q * 4;
    char* wp0 = wbase + (((0 * 4 + rl) * 16 + (q ^ ((0 * 4 + rl) & 7))) * 16);
    char* wp1 = wbase + (((1 * 4 + rl) * 16 + (q ^ ((1 * 4 + rl) & 7))) * 16);
    char* wp2 = wbase + (((2 * 4 + rl) * 16 + (q ^ ((2 * 4 + rl) & 7))) * 16);
    char* wp3 = wbase + (((3 * 4 + rl) * 16 + (q ^ ((3 * 4 + rl) & 7))) * 16);
    const int s7 = c & 7;
    const char* rd0 = wbase + ((c * 16 + ((g * 2 + 0) ^ s7)) * 16);
    const char* rd1 = wbase + ((c * 16 + ((g * 2 + 1) ^ s7)) * 16);

    f32x4 acc0 = {0.f, 0.f, 0.f, 0.f}, acc1 = {0.f, 0.f, 0.f, 0.f};
    f32x4 acc2 = {0.f, 0.f, 0.f, 0.f}, acc3 = {0.f, 0.f, 0.f, 0.f};

    float4 fA0, fA1, fA2, fA3, fB0, fB1, fB2, fB3;
    int4   aA0, aA1, aA2, aA3, aB0, aB1, aB2, aB3;

#define G2LOADG(ch, F0, F1, F2, F3, A0, A1, A2, A3) {                   \
    F0 = *(const float4*)(gF0 + (ch) * 64);                             \
    F1 = *(const float4*)(gF1 + (ch) * 64);                             \
    F2 = *(const float4*)(gF2 + (ch) * 64);                             \
    F3 = *(const float4*)(gF3 + (ch) * 64);                             \
    A0 = *(const int4*)(gA0 + (ch) * 64);                               \
    A1 = *(const int4*)(gA1 + (ch) * 64);                               \
    A2 = *(const int4*)(gA2 + (ch) * 64);                               \
    A3 = *(const int4*)(gA3 + (ch) * 64); }

#define G2STORE_LDS(F0, F1, F2, F3, A0, A1, A2, A3) {                   \
    *(float4*)wp0 = F0; *(float4*)wp1 = F1;                             \
    *(float4*)wp2 = F2; *(float4*)wp3 = F3;                             \
    *(int4*)(wp0 + 4096) = A0; *(int4*)(wp1 + 4096) = A1;               \
    *(int4*)(wp2 + 4096) = A2; *(int4*)(wp3 + 4096) = A3; }

#define G2CV4(e4, m4, ah, al_, o) {                                     \
    short h_, l_;                                                       \
    splitw((m4.x == 1) ? fmaf(e4.x, ke, ce) : 0.f, h_, l_);             \
    ah[o + 0] = h_; al_[o + 0] = l_;                                    \
    splitw((m4.y == 1) ? fmaf(e4.y, ke, ce) : 0.f, h_, l_);             \
    ah[o + 1] = h_; al_[o + 1] = l_;                                    \
    splitw((m4.z == 1) ? fmaf(e4.z, ke, ce) : 0.f, h_, l_);             \
    ah[o + 2] = h_; al_[o + 2] = l_;                                    \
    splitw((m4.w == 1) ? fmaf(e4.w, ke, ce) : 0.f, h_, l_);             \
    ah[o + 3] = h_; al_[o + 3] = l_; }

#define G2KS(ksg, off) {                                                \
    float4 e0 = *(const float4*)(rd0 + (off));                          \
    float4 e1 = *(const float4*)(rd1 + (off));                          \
    int4   m0 = *(const int4*)(rd0 + 4096 + (off));                     \
    int4   m1 = *(const int4*)(rd1 + 4096 + (off));                     \
    bf16x8 bb0 = hfb[(0 * 16 + (ksg)) * 64 + l];                        \
    bf16x8 bb1 = hfb[(1 * 16 + (ksg)) * 64 + l];                        \
    bf16x8 bb2 = hfb[(2 * 16 + (ksg)) * 64 + l];                        \
    bf16x8 bb3 = hfb[(3 * 16 + (ksg)) * 64 + l];                        \
    bf16x8 ah, al_;                                                     \
    G2CV4(e0, m0, ah, al_, 0);                                          \
    G2CV4(e1, m1, ah, al_, 4);                                          \
    acc0 = __builtin_amdgcn_mfma_f32_16x16x32_bf16(ah, bb0, acc0, 0, 0, 0); \
    acc0 = __builtin_amdgcn_mfma_f32_16x16x32_bf16(al_, bb0, acc0, 0, 0, 0); \
    acc1 = __builtin_amdgcn_mfma_f32_16x16x32_bf16(ah, bb1, acc1, 0, 0, 0); \
    acc1 = __builtin_amdgcn_mfma_f32_16x16x32_bf16(al_, bb1, acc1, 0, 0, 0); \
    acc2 = __builtin_amdgcn_mfma_f32_16x16x32_bf16(ah, bb2, acc2, 0, 0, 0); \
    acc2 = __builtin_amdgcn_mfma_f32_16x16x32_bf16(al_, bb2, acc2, 0, 0, 0); \
    acc3 = __builtin_amdgcn_mfma_f32_16x16x32_bf16(ah, bb3, acc3, 0, 0, 0); \
    acc3 = __builtin_amdgcn_mfma_f32_16x16x32_bf16(al_, bb3, acc3, 0, 0, 0); }

    // ---- Phase A: stream loop, 2-deep register prefetch ----
    G2LOADG(0, fA0, fA1, fA2, fA3, aA0, aA1, aA2, aA3);
    G2LOADG(1, fB0, fB1, fB2, fB3, aB0, aB1, aB2, aB3);
    #pragma unroll
    for (int ip = 0; ip < 4; ++ip) {
        G2STORE_LDS(fA0, fA1, fA2, fA3, aA0, aA1, aA2, aA3);
        if (ip < 3) G2LOADG(2 * ip + 2, fA0, fA1, fA2, fA3, aA0, aA1, aA2, aA3);
        G2KS(4 * ip + 0, 0);
        G2KS(4 * ip + 1, 128);
        G2STORE_LDS(fB0, fB1, fB2, fB3, aB0, aB1, aB2, aB3);
        if (ip < 3) G2LOADG(2 * ip + 3, fB0, fB1, fB2, fB3, aB0, aB1, aB2, aB3);
        G2KS(4 * ip + 2, 0);
        G2KS(4 * ip + 3, 128);
    }

    // ---- Phase B: per-wave epilogue (scratch = wave tile, seq. aliasing) ----
    char* Sw = wbase;
    const long long outbase = (long long)li * O_ + ((r16 & 127) * 16);

    // G1: feat_opt = elu(feat0@W1+b1)@W2
    f32x4 fo[2];
    {
        const float* f0b = feat0 + rowg * FIN;
        f32x4 h1[8];
        #pragma unroll
        for (int nf = 0; nf < 8; ++nf) h1[nf] = (f32x4){0.f, 0.f, 0.f, 0.f};
        #pragma unroll
        for (int ks = 0; ks < 2; ++ks) {
            const float* ap = f0b + c * FIN + ks * 32 + g * 8;
            float4 x0 = *(const float4*)ap;
            float4 x1 = *(const float4*)(ap + 4);
            bf16x8 a;
            a[0] = (short)f2b(x0.x); a[1] = (short)f2b(x0.y);
            a[2] = (short)f2b(x0.z); a[3] = (short)f2b(x0.w);
            a[4] = (short)f2b(x1.x); a[5] = (short)f2b(x1.y);
            a[6] = (short)f2b(x1.z); a[7] = (short)f2b(x1.w);
            #pragma unroll
            for (int nf = 0; nf < 8; ++nf)
                h1[nf] = __builtin_amdgcn_mfma_f32_16x16x32_bf16(
                    a, gW1f[(nf * 2 + ks) * 64 + l], h1[nf], 0, 0, 0);
        }
        #pragma unroll
        for (int nf = 0; nf < 8; ++nf) {
            float bb = w0b1[nf * 16 + c];
            #pragma unroll
            for (int reg = 0; reg < 4; ++reg) {
                int row = g * 4 + reg;
                *(unsigned short*)(Sw + row * 272 + (nf * 16 + c) * 2) =
                    f2b(elu_f(h1[nf][reg] + bb));
            }
        }
        fo[0] = (f32x4){0.f, 0.f, 0.f, 0.f};
        fo[1] = (f32x4){0.f, 0.f, 0.f, 0.f};
        #pragma unroll
        for (int ks = 0; ks < 4; ++ks) {
            bf16x8 a = *(const bf16x8*)(Sw + c * 272 + ks * 64 + g * 16);
            #pragma unroll
            for (int nf2 = 0; nf2 < 2; ++nf2)
                fo[nf2] = __builtin_amdgcn_mfma_f32_16x16x32_bf16(
                    a, gW2f[(nf2 * 4 + ks) * 64 + l], fo[nf2], 0, 0, 0);
        }
    }

    // G3: typed = agg @ Wt  (acc -> hi/lo scratch transpose -> MFMA)
    f32x4 ty[6];
    {
        char* aggH = Sw;
        char* aggL = Sw + 2304;
        #pragma unroll
        for (int reg = 0; reg < 4; ++reg) {
            int row = g * 4 + reg;
            short h, lo;
            splitw(acc0[reg], h, lo);
            *(short*)(aggH + row * 144 + (0 * 16 + c) * 2) = h;
            *(short*)(aggL + row * 144 + (0 * 16 + c) * 2) = lo;
            splitw(acc1[reg], h, lo);
            *(short*)(aggH + row * 144 + (1 * 16 + c) * 2) = h;
            *(short*)(aggL + row * 144 + (1 * 16 + c) * 2) = lo;
            splitw(acc2[reg], h, lo);
            *(short*)(aggH + row * 144 + (2 * 16 + c) * 2) = h;
            *(short*)(aggL + row * 144 + (2 * 16 + c) * 2) = lo;
            splitw(acc3[reg], h, lo);
            *(short*)(aggH + row * 144 + (3 * 16 + c) * 2) = h;
            *(short*)(aggL + row * 144 + (3 * 16 + c) * 2) = lo;
        }
        #pragma unroll
        for (int nf = 0; nf < 6; ++nf) ty[nf] = (f32x4){0.f, 0.f, 0.f, 0.f};
        #pragma unroll
        for (int ks = 0; ks < 2; ++ks) {
            bf16x8 aH = *(const bf16x8*)(aggH + c * 144 + ks * 64 + g * 16);
            bf16x8 aL = *(const bf16x8*)(aggL + c * 144 + ks * 64 + g * 16);
            #pragma unroll
            for (int nf = 0; nf < 6; ++nf) {
                bf16x8 bH = gWtH[(nf * 2 + ks) * 64 + l];
                bf16x8 bL = gWtL[(nf * 2 + ks) * 64 + l];
                ty[nf] = __builtin_amdgcn_mfma_f32_16x16x32_bf16(aH, bH, ty[nf], 0, 0, 0);
                ty[nf] = __builtin_amdgcn_mfma_f32_16x16x32_bf16(aL, bH, ty[nf], 0, 0, 0);
                ty[nf] = __builtin_amdgcn_mfma_f32_16x16x32_bf16(aH, bL, ty[nf], 0, 0, 0);
            }
        }
    }

    // G4: mas_w = elu(typed@om1+b1)@om2 + b2  (ty -> hi/lo scratch -> MFMA)
    float p[4] = {0.f, 0.f, 0.f, 0.f};
    {
        char* tyH = Sw;
        char* tyL = Sw + 3328;
        #pragma unroll
        for (int nf = 0; nf < 6; ++nf)
            #pragma unroll
            for (int reg = 0; reg < 4; ++reg) {
                int row = g * 4 + reg;
                short h, lo; splitw(ty[nf][reg], h, lo);
                *(short*)(tyH + row * 208 + (nf * 16 + c) * 2) = h;
                *(short*)(tyL + row * 208 + (nf * 16 + c) * 2) = lo;
            }
        f32x4 h2[8];
        #pragma unroll
        for (int nf = 0; nf < 8; ++nf) h2[nf] = (f32x4){0.f, 0.f, 0.f, 0.f};
        #pragma unroll
        for (int ks = 0; ks < 3; ++ks) {
            bf16x8 aH = *(const bf16x8*)(tyH + c * 208 + ks * 64 + g * 16);
            bf16x8 aL = *(const bf16x8*)(tyL + c * 208 + ks * 64 + g * 16);
            #pragma unroll
            for (int nf = 0; nf < 8; ++nf) {
                bf16x8 bH = gO1H[(nf * 3 + ks) * 64 + l];
                bf16x8 bL = gO1L[(nf * 3 + ks) * 64 + l];
                h2[nf] = __builtin_amdgcn_mfma_f32_16x16x32_bf16(aH, bH, h2[nf], 0, 0, 0);
                h2[nf] = __builtin_amdgcn_mfma_f32_16x16x32_bf16(aL, bH, h2[nf], 0, 0, 0);
                h2[nf] = __builtin_amdgcn_mfma_f32_16x16x32_bf16(aH, bL, h2[nf], 0, 0, 0);
            }
        }
        #pragma unroll
        for (int nf = 0; nf < 8; ++nf) {
            float o2 = om2v[nf * 16 + c];
            float bb = omb1[nf * 16 + c];
            #pragma unroll
            for (int reg = 0; reg < 4; ++reg)
                p[reg] += elu_f(h2[nf][reg] + bb) * o2;
        }
        const float ob2 = omb2[0];
        #pragma unroll
        for (int reg = 0; reg < 4; ++reg) {
            #pragma unroll
            for (int off = 1; off < 16; off <<= 1)
                p[reg] += __shfl_xor(p[reg], off, 64);
            p[reg] += ob2;
        }
    }

    // epilogue: out = leaky_relu(feat_opt + b2 + mas_w)
    #pragma unroll
    for (int nf2 = 0; nf2 < 2; ++nf2) {
        float b2v = w0b2[nf2 * 16 + c];
        #pragma unroll
        for (int reg = 0; reg < 4; ++reg) {
            long long orow = outbase + g * 4 + reg;
            float val = fo[nf2][reg] + b2v + p[reg];
            val = val >= 0.f ? val : 0.2f * val;
            out[orow * DOUT + nf2 * 16 + c] = val;
        }
    }
#undef G2LOADG
#undef G2STORE_LDS
#undef G2CV4
#undef G2KS
}

// ---------------------------------------------------------------------------
extern "C" void kernel_launch(void* const* d_in, const int* in_sizes, int n_in,
                              void* d_out, int out_size, void* d_ws, size_t ws_size,
                              hipStream_t stream) {
    const float* feat0 = (const float*)d_in[0];
    const float* feat1 = (const float*)d_in[1];
    const float* feat2 = (const float*)d_in[2];
    const int*   adj   = (const int*)d_in[3];
    const int*   bidx  = (const int*)d_in[4];
    const float* w0_w1 = (const float*)d_in[5];
    const float* w0_b1 = (const float*)d_in[6];
    const float* w0_w2 = (const float*)d_in[7];
    const float* w0_b2 = (const float*)d_in[8];
    const float* v     = (const float*)d_in[9];
    const float* coeff = (const float*)d_in[10];
    const float* e_w1  = (const float*)d_in[11];
    const float* e_b1  = (const float*)d_in[12];
    const float* e_w2  = (const float*)d_in[13];
    const float* e_b2  = (const float*)d_in[14];
    const float* om_w1 = (const float*)d_in[15];
    const float* om_b1 = (const float*)d_in[16];
    const float* om_w2 = (const float*)d_in[17];
    const float* om_b2 = (const float*)d_in[18];
    float* out = (float*)d_out;
    char*  wsb = (char*)d_ws;

    const int bsel = in_sizes[4];              // 32

    float*  ws_scal = (float*)wsb;                    // 64 B
    bf16x8* ws_w1f  = (bf16x8*)(wsb + 4096);          // 16 KB
    bf16x8* ws_w2f  = (bf16x8*)(wsb + 20480);         // 8 KB
    bf16x8* ws_wth  = (bf16x8*)(wsb + 28672);         // 12 KB
    bf16x8* ws_wtl  = (bf16x8*)(wsb + 40960);         // 12 KB
    bf16x8* ws_o1h  = (bf16x8*)(wsb + 53248);         // 24 KB
    bf16x8* ws_o1l  = (bf16x8*)(wsb + 77824);         // 24 KB
    bf16x8* ws_hf   = (bf16x8*)(wsb + 131072);        // 2 MB

    prep<<<15 + bsel * 4, 256, 0, stream>>>(e_w1, e_b1, e_w2, e_b2, coeff, v,
                                            w0_w1, w0_w2, om_w1, feat1, bidx,
                                            ws_scal, ws_w1f, ws_w2f,
                                            ws_wth, ws_wtl, ws_o1h, ws_o1l,
                                            ws_hf);
    gfused<<<bsel * 32, 256, 0, stream>>>(feat2, adj, feat0, bidx,
                                          ws_scal, ws_hf,
                                          ws_w1f, ws_w2f, ws_wth, ws_wtl,
                                          ws_o1h, ws_o1l,
                                          w0_b1, w0_b2, om_b1, om_w2, om_b2,
                                          out);
}